// Round 1
// 271.208 us; speedup vs baseline: 1.1377x; 1.1377x over previous
//
#include <hip/hip_runtime.h>
#include <stdint.h>

// VectorQuantization: out[n] = codebook[argmax_k dot(x[n], codebook[k])]
// (L2-normalize is a positive row-scalar -> argmax-invariant -> skipped)
//
// R4: port the GEMM to the 256x256 counted-vmcnt phase-interleaved schedule
// (T3+T4+T5): 512 threads / 8 waves (4M x 2N, 64x128 per wave), BK=32,
// FOUR single-K-tile LDS buffers (128 KiB) with lookahead-3 staging so the
// stage target is provably idle from issue through landing; one counted
// s_waitcnt vmcnt(8) per K-tile (never a vmcnt(0) drain in steady state),
// raw s_barrier (no compiler-inserted drain), s_setprio(1) around each
// 16-MFMA cluster.
// Epilogue cheapened: accumulator init +4.0 biases all sims positive so
// u32 bit-compare is monotone (free transform); a 6-bit inverted (tile,j)
// code packed into low mantissa bits (<=64 ulp ~1.5e-5 << MARGIN) halves
// top-2 register state and makes the update 6 branchless VALU ops.
// Winner lane recovered post-butterfly by ballot; lowest-index tie-break
// preserved. Bias cancels in recheck's relative margin test -> recheck
// kernel unchanged (still exact-fp64 disambiguation within MARGIN).
//
// Carried from R2/R3: zero-bank-conflict XOR chunk swizzle on LDS
// (verified SQ_LDS_BANK_CONFLICT == 0), fp16 single-pass GEMM + recheck.

typedef _Float16 half8 __attribute__((ext_vector_type(8)));
typedef _Float16 half4v __attribute__((ext_vector_type(4)));
typedef float f32x4 __attribute__((ext_vector_type(4)));

#define M_ROWS 8192
#define DIM 512
#define K_CODES 16384
#define BM 256
#define BN 256
#define BK 32
#define NSPLIT 16
#define NT ((K_CODES / NSPLIT) / BN) /* 4 col-tiles per block */
#define KT_CT (DIM / BK)             /* 16 K-tiles per col-tile */
#define G (NT * KT_CT)               /* 64 K-tiles per block */
#define MARGIN 2.0e-3f
#define BIAS 4.0f

typedef __attribute__((address_space(1))) uint32_t as1_u32;
typedef __attribute__((address_space(3))) uint32_t as3_u32;

__device__ __forceinline__ void gll16(const void* g, void* l) {
  // async global->LDS, 16B/lane; LDS dest = wave-uniform base + lane*16
  __builtin_amdgcn_global_load_lds((const as1_u32*)(uintptr_t)g,
                                   (as3_u32*)(uintptr_t)l, 16, 0, 0);
}

__global__ void to_f16(const float* __restrict__ src, _Float16* __restrict__ dst, int n4) {
  int i = blockIdx.x * 256 + threadIdx.x;
  if (i >= n4) return;
  const float4 v = reinterpret_cast<const float4*>(src)[i];
  half4v h = {(_Float16)v.x, (_Float16)v.y, (_Float16)v.z, (_Float16)v.w};
  reinterpret_cast<half4v*>(dst)[i] = h;
}

__global__ __launch_bounds__(512, 2) void vq_argmax(
    const _Float16* __restrict__ xh, const _Float16* __restrict__ ch,
    float* __restrict__ pv, int* __restrict__ pi) {
  // 4 rotating single-K-tile buffers x {A,B} x (256 rows x 32 k) = 128 KiB
  __shared__ _Float16 lds[4][2][BM * BK];

  const int tid = threadIdx.x;
  const int lane = tid & 63;
  const int w = tid >> 6;
  const int wm = w >> 1, wn = w & 1;       // 4M x 2N wave grid
  const int l15 = lane & 15, quad = lane >> 4;
  const int row0 = blockIdx.x * BM;
  const int split = blockIdx.y;
  // swizzled k-chunk element offset for this lane's fragment reads
  const int kq = ((quad ^ ((l15 >> 1) & 3)) << 3);
  const int aoff = (wm * 64 + l15) * BK + kq;
  const int boff = (wn * 128 + l15) * BK + kq;

  // staging: slot s = r*512+tid holds logical chunk (row=s>>2, kc=(s&3)^((row>>1)&3))
  int eoff0, eoff1, doff0, doff1;
  {
    const int s1 = 512 + tid;
    const int r0 = tid >> 2, r1 = s1 >> 2;
    eoff0 = r0 * DIM + ((((tid & 3) ^ ((r0 >> 1) & 3))) << 3);
    eoff1 = r1 * DIM + ((((s1 & 3) ^ ((r1 >> 1) & 3))) << 3);
    doff0 = (tid & 448) << 3;
    doff1 = (512 + (tid & 448)) << 3;
  }
  const _Float16* Asrc = xh + (size_t)row0 * DIM;
  const _Float16* Bsrc = ch + (size_t)split * (K_CODES / NSPLIT) * DIM;

  auto stageA = [&](int t) {
    const int b = t & 3, ko = (t & 15) * BK;
    const _Float16* g = Asrc + ko;
    _Float16* l = &lds[b][0][0];
    gll16(g + eoff0, l + doff0);
    gll16(g + eoff1, l + doff1);
  };
  auto stageB = [&](int t) {
    const int b = t & 3, ko = (t & 15) * BK;
    const _Float16* g = Bsrc + (size_t)(t >> 4) * (BN * DIM) + ko;
    _Float16* l = &lds[b][1][0];
    gll16(g + eoff0, l + doff0);
    gll16(g + eoff1, l + doff1);
  };

  // packed top-2 keys per (i,r) row-slot: high bits = biased-sim f32 bits,
  // low 6 bits = inverted (coltile,j) code (bigger key = better / lower idx)
  unsigned K1[4][4], K2[4][4];
#pragma unroll
  for (int i = 0; i < 4; ++i)
#pragma unroll
    for (int r = 0; r < 4; ++r) { K1[i][r] = 0u; K2[i][r] = 0u; }

  f32x4 acc[4][8];

  // prologue: stage K-tiles 0,1,2 (12 loads/wave); wait kt0 landed, sync
  stageA(0); stageB(0); stageA(1); stageB(1); stageA(2); stageB(2);
  asm volatile("s_waitcnt vmcnt(8)" ::: "memory");
  __builtin_amdgcn_s_barrier();
  asm volatile("" ::: "memory");

#pragma unroll 1
  for (int kt = 0; kt < G; ++kt) {
    const int bk = kt & 3;
    if ((kt & 15) == 0) {
#pragma unroll
      for (int i = 0; i < 4; ++i)
#pragma unroll
        for (int j = 0; j < 8; ++j) acc[i][j] = (f32x4){BIAS, BIAS, BIAS, BIAS};
    }
    const _Float16* Ab = &lds[bk][0][0];
    const _Float16* Bb = &lds[bk][1][0];

    half8 Af[4];
#pragma unroll
    for (int i = 0; i < 4; ++i) Af[i] = *(const half8*)&Ab[aoff + i * (16 * BK)];
    // ---- phase 1: A + B[0..3], stage A(kt+3), 16 MFMA ----
    {
      half8 Bf[4];
#pragma unroll
      for (int j = 0; j < 4; ++j) Bf[j] = *(const half8*)&Bb[boff + j * (16 * BK)];
      if (kt + 3 < G) stageA(kt + 3);
      __builtin_amdgcn_s_barrier();
      __builtin_amdgcn_s_setprio(1);
#pragma unroll
      for (int i = 0; i < 4; ++i)
#pragma unroll
        for (int j = 0; j < 4; ++j)
          acc[i][j] = __builtin_amdgcn_mfma_f32_16x16x32_f16(Af[i], Bf[j], acc[i][j], 0, 0, 0);
      __builtin_amdgcn_s_setprio(0);
      __builtin_amdgcn_s_barrier();
    }
    // ---- phase 2: B[4..7], stage B(kt+3), 16 MFMA, counted vmcnt ----
    {
      half8 Bf[4];
#pragma unroll
      for (int j = 0; j < 4; ++j) Bf[j] = *(const half8*)&Bb[boff + (j + 4) * (16 * BK)];
      if (kt + 3 < G) stageB(kt + 3);
      __builtin_amdgcn_s_barrier();
      __builtin_amdgcn_s_setprio(1);
#pragma unroll
      for (int i = 0; i < 4; ++i)
#pragma unroll
        for (int j = 0; j < 4; ++j)
          acc[i][j + 4] = __builtin_amdgcn_mfma_f32_16x16x32_f16(Af[i], Bf[j], acc[i][j + 4], 0, 0, 0);
      __builtin_amdgcn_s_setprio(0);
      // kt+1's tiles were staged during kt-2; everything newer = stages for
      // kt+2,kt+3 = 8 loads -> vmcnt(8) steady state, 4/0 at the tail
      if (kt < G - 3)       asm volatile("s_waitcnt vmcnt(8)" ::: "memory");
      else if (kt == G - 3) asm volatile("s_waitcnt vmcnt(4)" ::: "memory");
      else if (kt == G - 2) asm volatile("s_waitcnt vmcnt(0)" ::: "memory");
      __builtin_amdgcn_s_barrier();
      asm volatile("" ::: "memory");
    }

    // per col-tile: fold 128 candidates/lane into packed top-2 (6 VALU each)
    if ((kt & 15) == 15) {
      const unsigned icb = 63u - (unsigned)(kt >> 4) * 8u;  // icode = icb - j
#pragma unroll
      for (int j = 0; j < 8; ++j) {
        const unsigned xo = 63u ^ (icb - (unsigned)j);
#pragma unroll
        for (int i = 0; i < 4; ++i)
#pragma unroll
          for (int r = 0; r < 4; ++r) {
            const unsigned k = (__float_as_uint(acc[i][j][r]) | 63u) ^ xo;
            const bool gt = k > K1[i][r];
            const unsigned t2 = K2[i][r] > k ? K2[i][r] : k;
            K2[i][r] = gt ? K1[i][r] : t2;
            K1[i][r] = gt ? k : K1[i][r];
          }
      }
    }
  }

  // butterfly-merge top-2 across the 16 column-lanes of each quad, recover
  // winner lane via ballot (first set bit = lowest l15 = lowest index on tie)
  const int nb = split * (K_CODES / NSPLIT);
#pragma unroll
  for (int i = 0; i < 4; ++i)
#pragma unroll
    for (int r = 0; r < 4; ++r) {
      const unsigned p1 = K1[i][r], p2 = K2[i][r];
      unsigned a1 = p1, a2 = p2;
#pragma unroll
      for (int d = 1; d < 16; d <<= 1) {
        const unsigned b1 = (unsigned)__shfl_xor((int)a1, d);
        const unsigned b2 = (unsigned)__shfl_xor((int)a2, d);
        const unsigned hi = a1 > b1 ? a1 : b1;
        const unsigned lo = a1 > b1 ? b1 : a1;
        const unsigned mx = a2 > b2 ? a2 : b2;
        a1 = hi;
        a2 = lo > mx ? lo : mx;
      }
      const unsigned long long bl1 = __ballot(p1 == a1);
      const int s1 = __ffsll((unsigned long long)((bl1 >> (quad * 16)) & 0xFFFFull)) - 1;
      const unsigned long long bl2 = __ballot((p2 == a2) || (p1 == a2 && l15 != s1));
      const int s2 = __ffsll((unsigned long long)((bl2 >> (quad * 16)) & 0xFFFFull)) - 1;
      if (l15 == 0) {
        const int code1 = 63 - (int)(a1 & 63u);
        const int code2 = 63 - (int)(a2 & 63u);
        const int col1 = nb + (code1 >> 3) * BN + wn * 128 + (code1 & 7) * 16 + s1;
        const int col2 = nb + (code2 >> 3) * BN + wn * 128 + (code2 & 7) * 16 + s2;
        const int rl = wm * 64 + i * 16 + quad * 4 + r;
        const size_t o = (size_t)(row0 + rl) * 64 + (size_t)(split * 4 + wn * 2);
        pv[o] = __uint_as_float(a1); pi[o] = col1;      // values stay +4-biased;
        pv[o + 1] = __uint_as_float(a2); pi[o + 1] = col2;  // margin test is relative
      }
    }
}

__global__ void recheck_gather(const float* __restrict__ pv, const int* __restrict__ pi,
                               const float* __restrict__ x, const float* __restrict__ cb,
                               float* __restrict__ out) {
  const int row = blockIdx.x;
  const int lane = threadIdx.x;   // 64 candidates = 16 splits x 2 classes x top-2
  float v = pv[(size_t)row * 64 + lane];
  int ci = pi[(size_t)row * 64 + lane];

  // wave max with lowest-index tie-break
  float m1 = v; int mi1 = ci;
#pragma unroll
  for (int d = 1; d < 64; d <<= 1) {
    float ov = __shfl_xor(m1, d);
    int oi = __shfl_xor(mi1, d);
    if (ov > m1 || (ov == m1 && oi < mi1)) { m1 = ov; mi1 = oi; }
  }

  const bool flag = (v >= m1 - MARGIN);
  const unsigned long long mask = __ballot(flag);
  int winner;
  if (__popcll(mask) == 1) {
    winner = mi1;   // approx winner is >=14-sigma clear of every other candidate
  } else {
    // exact fp64 dot from original fp32 inputs for each flagged candidate
    double e = -1.0e300;
    if (flag) {
      const float* xr = x + (size_t)row * DIM;
      const float* cr = cb + (size_t)ci * DIM;
      double s = 0.0;
#pragma unroll 4
      for (int t = 0; t < DIM; t += 4) {
        const float4 a = *(const float4*)(xr + t);
        const float4 b = *(const float4*)(cr + t);
        s += (double)a.x * b.x + (double)a.y * b.y + (double)a.z * b.z + (double)a.w * b.w;
      }
      e = s;
    }
    int ei = flag ? ci : 0x7fffffff;
#pragma unroll
    for (int d = 1; d < 64; d <<= 1) {
      double oe = __shfl_xor(e, d);
      int oi = __shfl_xor(ei, d);
      if (oe > e || (oe == e && oi < ei)) { e = oe; ei = oi; }
    }
    winner = ei;
  }

  const float4* src = (const float4*)(cb + (size_t)winner * DIM);
  float4* dst = (float4*)(out + (size_t)row * DIM);
  dst[lane] = src[lane];         // 512 f32 = 128 float4, 64 lanes x 2
  dst[lane + 64] = src[lane + 64];
}

extern "C" void kernel_launch(void* const* d_in, const int* in_sizes, int n_in,
                              void* d_out, int out_size, void* d_ws, size_t ws_size,
                              hipStream_t stream) {
  const float* x = (const float*)d_in[0];
  const float* cb = (const float*)d_in[1];
  float* out = (float*)d_out;

  // ws layout: x_f16(8MB) c_f16(16MB) pv(2MB) pi(2MB)
  _Float16* xh = (_Float16*)d_ws;
  _Float16* ch = xh + (size_t)M_ROWS * DIM;
  float* pv = (float*)(ch + (size_t)K_CODES * DIM);
  int* pi = (int*)(pv + (size_t)M_ROWS * NSPLIT * 2 * 2);

  to_f16<<<(M_ROWS * DIM / 4) / 256, 256, 0, stream>>>(x, xh, M_ROWS * DIM / 4);
  to_f16<<<(K_CODES * DIM / 4) / 256, 256, 0, stream>>>(cb, ch, K_CODES * DIM / 4);
  vq_argmax<<<dim3(M_ROWS / BM, NSPLIT), 512, 0, stream>>>(xh, ch, pv, pi);
  recheck_gather<<<M_ROWS, 64, 0, stream>>>(pv, pi, x, cb, out);
}

// Round 2
// 251.152 us; speedup vs baseline: 1.2286x; 1.0799x over previous
//
#include <hip/hip_runtime.h>
#include <stdint.h>

// VectorQuantization: out[n] = codebook[argmax_k dot(x[n], codebook[k])]
// (L2-normalize is a positive row-scalar -> argmax-invariant -> skipped)
//
// R5: single-barrier K-tile schedule. R4's 2-phase/4-barrier lockstep put the
// CU-wide LDS read burst (~570 cyc) serially in front of every MFMA window
// (MfmaUtil stuck at 34%). Now: per K-tile, all 12 fragment ds_read_b128 are
// issued up front in need-order, stages follow, then the 32-MFMA run; the
// compiler's counted lgkmcnt lets the B[4..7] reads complete UNDER the
// j=0..3 MFMA window, and the single end-of-tile barrier lets waves drift so
// one wave's MFMA covers another's LDS service. Counted vmcnt(8) + 4-buffer
// lookahead-3 staging carried from R4. Top-2 fold split into two halves
// interleaved between MFMA j-groups (VALU co-issues under MFMA pipe).
//
// Race ledger (1 barrier/kt): during kt, the only LDS reads are from buffer
// kt&3; stages issued during kt target buffer (kt+3)&3 == (kt-1)&3, whose
// last reads happened during kt-1, before kt-1's end barrier -> no
// stage-vs-read overlap. Reads of buffer kt&3 are safe because kt's stages
// were issued at kt-3 and own-wave completion is forced by the vmcnt(8) at
// end of kt-1; the barrier makes it all-waves. Prologue/tail counts verified
// (12 outstanding steady; 8/4/0 drain at G-3/G-2).
//
// Carried: zero-bank-conflict XOR chunk swizzle (SQ_LDS_BANK_CONFLICT == 0),
// packed-key top-2 epilogue (+4.0 bias -> u32-monotone, 6-bit inverted
// (tile,j) code in low mantissa bits, <=64 ulp << MARGIN), ballot winner-lane
// recovery, exact-fp64 recheck within MARGIN. to_f16 passes merged into one
// launch.

typedef _Float16 half8 __attribute__((ext_vector_type(8)));
typedef _Float16 half4v __attribute__((ext_vector_type(4)));
typedef float f32x4 __attribute__((ext_vector_type(4)));

#define M_ROWS 8192
#define DIM 512
#define K_CODES 16384
#define BM 256
#define BN 256
#define BK 32
#define NSPLIT 16
#define NT ((K_CODES / NSPLIT) / BN) /* 4 col-tiles per block */
#define KT_CT (DIM / BK)             /* 16 K-tiles per col-tile */
#define G (NT * KT_CT)               /* 64 K-tiles per block */
#define MARGIN 2.0e-3f
#define BIAS 4.0f

typedef __attribute__((address_space(1))) uint32_t as1_u32;
typedef __attribute__((address_space(3))) uint32_t as3_u32;

__device__ __forceinline__ void gll16(const void* g, void* l) {
  // async global->LDS, 16B/lane; LDS dest = wave-uniform base + lane*16
  __builtin_amdgcn_global_load_lds((const as1_u32*)(uintptr_t)g,
                                   (as3_u32*)(uintptr_t)l, 16, 0, 0);
}

__global__ void to_f16_all(const float* __restrict__ x, const float* __restrict__ cb,
                           _Float16* __restrict__ xh, _Float16* __restrict__ ch) {
  const int NX = M_ROWS * DIM / 4;
  int i = blockIdx.x * 256 + threadIdx.x;
  float4 v;
  if (i < NX) v = reinterpret_cast<const float4*>(x)[i];
  else        v = reinterpret_cast<const float4*>(cb)[i - NX];
  half4v h = {(_Float16)v.x, (_Float16)v.y, (_Float16)v.z, (_Float16)v.w};
  if (i < NX) reinterpret_cast<half4v*>(xh)[i] = h;
  else        reinterpret_cast<half4v*>(ch)[i - NX] = h;
}

__global__ __launch_bounds__(512, 2) void vq_argmax(
    const _Float16* __restrict__ xh, const _Float16* __restrict__ ch,
    float* __restrict__ pv, int* __restrict__ pi) {
  // 4 rotating single-K-tile buffers x {A,B} x (256 rows x 32 k) = 128 KiB
  __shared__ _Float16 lds[4][2][BM * BK];

  const int tid = threadIdx.x;
  const int lane = tid & 63;
  const int w = tid >> 6;
  const int wm = w >> 1, wn = w & 1;       // 4M x 2N wave grid
  const int l15 = lane & 15, quad = lane >> 4;
  const int row0 = blockIdx.x * BM;
  const int split = blockIdx.y;
  // swizzled k-chunk element offset for this lane's fragment reads
  const int kq = ((quad ^ ((l15 >> 1) & 3)) << 3);
  const int aoff = (wm * 64 + l15) * BK + kq;
  const int boff = (wn * 128 + l15) * BK + kq;

  // staging: slot s = r*512+tid holds logical chunk (row=s>>2, kc=(s&3)^((row>>1)&3))
  int eoff0, eoff1, doff0, doff1;
  {
    const int s1 = 512 + tid;
    const int r0 = tid >> 2, r1 = s1 >> 2;
    eoff0 = r0 * DIM + ((((tid & 3) ^ ((r0 >> 1) & 3))) << 3);
    eoff1 = r1 * DIM + ((((s1 & 3) ^ ((r1 >> 1) & 3))) << 3);
    doff0 = (tid & 448) << 3;
    doff1 = (512 + (tid & 448)) << 3;
  }
  const _Float16* Asrc = xh + (size_t)row0 * DIM;
  const _Float16* Bsrc = ch + (size_t)split * (K_CODES / NSPLIT) * DIM;

  auto stageA = [&](int t) {
    const int b = t & 3, ko = (t & 15) * BK;
    const _Float16* g = Asrc + ko;
    _Float16* l = &lds[b][0][0];
    gll16(g + eoff0, l + doff0);
    gll16(g + eoff1, l + doff1);
  };
  auto stageB = [&](int t) {
    const int b = t & 3, ko = (t & 15) * BK;
    const _Float16* g = Bsrc + (size_t)(t >> 4) * (BN * DIM) + ko;
    _Float16* l = &lds[b][1][0];
    gll16(g + eoff0, l + doff0);
    gll16(g + eoff1, l + doff1);
  };

  // packed top-2 keys per (i,r) row-slot: high bits = biased-sim f32 bits,
  // low 6 bits = inverted (coltile,j) code (bigger key = better / lower idx)
  unsigned K1[4][4], K2[4][4];
#pragma unroll
  for (int i = 0; i < 4; ++i)
#pragma unroll
    for (int r = 0; r < 4; ++r) { K1[i][r] = 0u; K2[i][r] = 0u; }

  f32x4 acc[4][8];

  auto fold = [&](int j0, int j1, int kt) {
    const unsigned icb = 63u - (unsigned)(kt >> 4) * 8u;  // icode = icb - j
#pragma unroll
    for (int j = j0; j < j1; ++j) {
      const unsigned xo = 63u ^ (icb - (unsigned)j);
#pragma unroll
      for (int i = 0; i < 4; ++i)
#pragma unroll
        for (int r = 0; r < 4; ++r) {
          const unsigned k = (__float_as_uint(acc[i][j][r]) | 63u) ^ xo;
          const bool gt = k > K1[i][r];
          const unsigned t2 = K2[i][r] > k ? K2[i][r] : k;
          K2[i][r] = gt ? K1[i][r] : t2;
          K1[i][r] = gt ? k : K1[i][r];
        }
    }
  };

  // prologue: stage K-tiles 0,1,2 (12 loads/wave); wait kt0 landed, sync
  stageA(0); stageB(0); stageA(1); stageB(1); stageA(2); stageB(2);
  asm volatile("s_waitcnt vmcnt(8)" ::: "memory");
  __builtin_amdgcn_s_barrier();
  asm volatile("" ::: "memory");

#pragma unroll 1
  for (int kt = 0; kt < G; ++kt) {
    const int bk = kt & 3;
    if ((kt & 15) == 0) {
#pragma unroll
      for (int i = 0; i < 4; ++i)
#pragma unroll
        for (int j = 0; j < 8; ++j) acc[i][j] = (f32x4){BIAS, BIAS, BIAS, BIAS};
    }
    const _Float16* Ab = &lds[bk][0][0];
    const _Float16* Bb = &lds[bk][1][0];

    // all 12 fragment reads up front, in need-order; counted lgkm waits let
    // B[4..7] complete under the j=0..3 MFMA window
    half8 A_[4], B_[8];
#pragma unroll
    for (int i = 0; i < 4; ++i) A_[i] = *(const half8*)&Ab[aoff + i * (16 * BK)];
#pragma unroll
    for (int j = 0; j < 8; ++j) B_[j] = *(const half8*)&Bb[boff + j * (16 * BK)];

    if (kt + 3 < G) { stageA(kt + 3); stageB(kt + 3); }

    __builtin_amdgcn_s_setprio(1);
#pragma unroll
    for (int j = 0; j < 4; ++j)
#pragma unroll
      for (int i = 0; i < 4; ++i)
        acc[i][j] = __builtin_amdgcn_mfma_f32_16x16x32_f16(A_[i], B_[j], acc[i][j], 0, 0, 0);
    __builtin_amdgcn_s_setprio(0);
    if ((kt & 15) == 15) fold(0, 4, kt);   // VALU half-fold under next MFMA group
    __builtin_amdgcn_s_setprio(1);
#pragma unroll
    for (int j = 4; j < 8; ++j)
#pragma unroll
      for (int i = 0; i < 4; ++i)
        acc[i][j] = __builtin_amdgcn_mfma_f32_16x16x32_f16(A_[i], B_[j], acc[i][j], 0, 0, 0);
    __builtin_amdgcn_s_setprio(0);
    if ((kt & 15) == 15) fold(4, 8, kt);

    // steady state: stages for kt+1..kt+3 outstanding (12); wait to 8 so
    // kt+1's buffer is landed. Tail drains 4 -> 0.
    if (kt < G - 3)       asm volatile("s_waitcnt vmcnt(8)" ::: "memory");
    else if (kt == G - 3) asm volatile("s_waitcnt vmcnt(4)" ::: "memory");
    else if (kt == G - 2) asm volatile("s_waitcnt vmcnt(0)" ::: "memory");
    __builtin_amdgcn_s_barrier();
    asm volatile("" ::: "memory");
  }

  // butterfly-merge top-2 across the 16 column-lanes of each quad, recover
  // winner lane via ballot (first set bit = lowest l15 = lowest index on tie)
  const int nb = split * (K_CODES / NSPLIT);
#pragma unroll
  for (int i = 0; i < 4; ++i)
#pragma unroll
    for (int r = 0; r < 4; ++r) {
      const unsigned p1 = K1[i][r], p2 = K2[i][r];
      unsigned a1 = p1, a2 = p2;
#pragma unroll
      for (int d = 1; d < 16; d <<= 1) {
        const unsigned b1 = (unsigned)__shfl_xor((int)a1, d);
        const unsigned b2 = (unsigned)__shfl_xor((int)a2, d);
        const unsigned hi = a1 > b1 ? a1 : b1;
        const unsigned lo = a1 > b1 ? b1 : a1;
        const unsigned mx = a2 > b2 ? a2 : b2;
        a1 = hi;
        a2 = lo > mx ? lo : mx;
      }
      const unsigned long long bl1 = __ballot(p1 == a1);
      const int s1 = __ffsll((unsigned long long)((bl1 >> (quad * 16)) & 0xFFFFull)) - 1;
      const unsigned long long bl2 = __ballot((p2 == a2) || (p1 == a2 && l15 != s1));
      const int s2 = __ffsll((unsigned long long)((bl2 >> (quad * 16)) & 0xFFFFull)) - 1;
      if (l15 == 0) {
        const int code1 = 63 - (int)(a1 & 63u);
        const int code2 = 63 - (int)(a2 & 63u);
        const int col1 = nb + (code1 >> 3) * BN + wn * 128 + (code1 & 7) * 16 + s1;
        const int col2 = nb + (code2 >> 3) * BN + wn * 128 + (code2 & 7) * 16 + s2;
        const int rl = wm * 64 + i * 16 + quad * 4 + r;
        const size_t o = (size_t)(row0 + rl) * 64 + (size_t)(split * 4 + wn * 2);
        pv[o] = __uint_as_float(a1); pi[o] = col1;      // values stay +4-biased;
        pv[o + 1] = __uint_as_float(a2); pi[o + 1] = col2;  // margin test is relative
      }
    }
}

__global__ void recheck_gather(const float* __restrict__ pv, const int* __restrict__ pi,
                               const float* __restrict__ x, const float* __restrict__ cb,
                               float* __restrict__ out) {
  const int row = blockIdx.x;
  const int lane = threadIdx.x;   // 64 candidates = 16 splits x 2 classes x top-2
  float v = pv[(size_t)row * 64 + lane];
  int ci = pi[(size_t)row * 64 + lane];

  // wave max with lowest-index tie-break
  float m1 = v; int mi1 = ci;
#pragma unroll
  for (int d = 1; d < 64; d <<= 1) {
    float ov = __shfl_xor(m1, d);
    int oi = __shfl_xor(mi1, d);
    if (ov > m1 || (ov == m1 && oi < mi1)) { m1 = ov; mi1 = oi; }
  }

  const bool flag = (v >= m1 - MARGIN);
  const unsigned long long mask = __ballot(flag);
  int winner;
  if (__popcll(mask) == 1) {
    winner = mi1;   // approx winner is >=14-sigma clear of every other candidate
  } else {
    // exact fp64 dot from original fp32 inputs for each flagged candidate
    double e = -1.0e300;
    if (flag) {
      const float* xr = x + (size_t)row * DIM;
      const float* cr = cb + (size_t)ci * DIM;
      double s = 0.0;
#pragma unroll 4
      for (int t = 0; t < DIM; t += 4) {
        const float4 a = *(const float4*)(xr + t);
        const float4 b = *(const float4*)(cr + t);
        s += (double)a.x * b.x + (double)a.y * b.y + (double)a.z * b.z + (double)a.w * b.w;
      }
      e = s;
    }
    int ei = flag ? ci : 0x7fffffff;
#pragma unroll
    for (int d = 1; d < 64; d <<= 1) {
      double oe = __shfl_xor(e, d);
      int oi = __shfl_xor(ei, d);
      if (oe > e || (oe == e && oi < ei)) { e = oe; ei = oi; }
    }
    winner = ei;
  }

  const float4* src = (const float4*)(cb + (size_t)winner * DIM);
  float4* dst = (float4*)(out + (size_t)row * DIM);
  dst[lane] = src[lane];         // 512 f32 = 128 float4, 64 lanes x 2
  dst[lane + 64] = src[lane + 64];
}

extern "C" void kernel_launch(void* const* d_in, const int* in_sizes, int n_in,
                              void* d_out, int out_size, void* d_ws, size_t ws_size,
                              hipStream_t stream) {
  const float* x = (const float*)d_in[0];
  const float* cb = (const float*)d_in[1];
  float* out = (float*)d_out;

  // ws layout: x_f16(8MB) c_f16(16MB) pv(2MB) pi(2MB)
  _Float16* xh = (_Float16*)d_ws;
  _Float16* ch = xh + (size_t)M_ROWS * DIM;
  float* pv = (float*)(ch + (size_t)K_CODES * DIM);
  int* pi = (int*)(pv + (size_t)M_ROWS * NSPLIT * 2 * 2);

  const int n4 = (M_ROWS + K_CODES) * DIM / 4;
  to_f16_all<<<n4 / 256, 256, 0, stream>>>(x, cb, xh, ch);
  vq_argmax<<<dim3(M_ROWS / BM, NSPLIT), 512, 0, stream>>>(xh, ch, pv, pi);
  recheck_gather<<<M_ROWS, 64, 0, stream>>>(pv, pi, x, cb, out);
}